// Round 1
// 1652.200 us; speedup vs baseline: 1.1876x; 1.1876x over previous
//
#include <hip/hip_runtime.h>

#define H 512
#define TWOH 1024
#define PDIM 4096
#define CDIM 151
#define RDIM 51
#define NDIM 4096
#define EDIM 32768
#define PSPLIT 4

typedef __attribute__((ext_vector_type(8))) short short8;
typedef __attribute__((ext_vector_type(4))) float f32x4;

__device__ __forceinline__ unsigned short f2bf(float f) {
    union { float f; unsigned u; } x;
    x.f = f;
    unsigned r = x.u + 0x7fffu + ((x.u >> 16) & 1u);
    return (unsigned short)(r >> 16);
}

__device__ __forceinline__ void gload_lds16(const void* g, void* l) {
    __builtin_amdgcn_global_load_lds((const __attribute__((address_space(1))) void*)g,
                                     (__attribute__((address_space(3))) void*)l, 16, 0, 0);
}

__global__ __launch_bounds__(256) void cvt_bf16_kernel(const float* __restrict__ src,
                                                       unsigned short* __restrict__ dst, int n) {
    int i = (blockIdx.x * 256 + threadIdx.x) * 4;
    if (i + 3 < n) {
        float4 v = *(const float4*)(src + i);
        ushort4 o;
        o.x = f2bf(v.x); o.y = f2bf(v.y); o.z = f2bf(v.z); o.w = f2bf(v.w);
        *(ushort4*)(dst + i) = o;
    }
}

// W_rc (51,4096) -> padded (64,4096) bf16, rows 51..63 zero
__global__ __launch_bounds__(256) void cvt_wrc_kernel(const float* __restrict__ src,
                                                      unsigned short* __restrict__ dst) {
    int i = (blockIdx.x * 256 + threadIdx.x) * 4;
    int r = i >> 12;
    int c = i & 4095;
    ushort4 o;
    if (r < RDIM) {
        float4 v = *(const float4*)(src + (size_t)r * PDIM + c);
        o.x = f2bf(v.x); o.y = f2bf(v.y); o.z = f2bf(v.z); o.w = f2bf(v.w);
    } else {
        o.x = 0; o.y = 0; o.z = 0; o.w = 0;
    }
    *(ushort4*)(dst + i) = o;
}

// edge_rep = edge_ctx @ W_pe.T + b_pe   (4096x1024), output bf16
__global__ __launch_bounds__(256) void gemm1_kernel(const unsigned short* __restrict__ A,
                                                    const unsigned short* __restrict__ B,
                                                    const float* __restrict__ bias,
                                                    unsigned short* __restrict__ Crep) {
    __shared__ __align__(16) unsigned short As[128 * 64];
    __shared__ __align__(16) unsigned short Bs[128 * 64];
    const int bx = blockIdx.x & 7;   // over N/128 = 8
    const int by = blockIdx.x >> 3;  // over M/128 = 32
    const int t = threadIdx.x;
    const int w = t >> 6, L = t & 63;
    const int quad = L >> 4, ln = L & 15;
    const int wr = (w >> 1) * 64, wc = (w & 1) * 64;
    const int srow = L >> 3, sc = L & 7;

    f32x4 acc[4][4] = {};
    for (int kt = 0; kt < 8; ++kt) {
        const int k0 = kt * 64;
#pragma unroll
        for (int s = 0; s < 4; ++s) {
            const int issue = w * 4 + s;
            const int row = issue * 8 + srow;
            const int ch = sc ^ (row & 7);
            gload_lds16(A + (size_t)(by * 128 + row) * H + k0 + ch * 8, &As[issue * 512]);
            gload_lds16(B + (size_t)(bx * 128 + row) * H + k0 + ch * 8, &Bs[issue * 512]);
        }
        __syncthreads();
#pragma unroll
        for (int kk = 0; kk < 2; ++kk) {
            short8 a[4], b[4];
#pragma unroll
            for (int i = 0; i < 4; ++i) {
                const int row = wr + 16 * i + ln;
                const int ch = (kk * 4 + quad) ^ (row & 7);
                a[i] = *(const short8*)&As[row * 64 + ch * 8];
            }
#pragma unroll
            for (int j = 0; j < 4; ++j) {
                const int row = wc + 16 * j + ln;
                const int ch = (kk * 4 + quad) ^ (row & 7);
                b[j] = *(const short8*)&Bs[row * 64 + ch * 8];
            }
#pragma unroll
            for (int i = 0; i < 4; ++i)
#pragma unroll
                for (int j = 0; j < 4; ++j)
                    acc[i][j] = __builtin_amdgcn_mfma_f32_16x16x32_bf16(a[i], b[j], acc[i][j], 0, 0, 0);
        }
        __syncthreads();
    }
#pragma unroll
    for (int i = 0; i < 4; ++i)
#pragma unroll
        for (int j = 0; j < 4; ++j) {
            const int col = bx * 128 + wc + 16 * j + ln;
            const float bv = bias[col];
#pragma unroll
            for (int r = 0; r < 4; ++r) {
                const int row = by * 128 + wr + 16 * i + quad * 4 + r;
                Crep[(size_t)row * TWOH + col] = f2bf(acc[i][j][r] + bv);
            }
        }
}

// Fused: GEMM2 (gathered edge_rep @ W_pc.T + b_pc) * uf -> LDS -> GEMM3 partial (@ W_rc.T)
// P reduction split across PSPLIT blocks; partials written to `part` [PSPLIT][EDIM][64] f32.
__global__ __launch_bounds__(256, 3) void fused_kernel(const unsigned short* __restrict__ Erep,
                                                       const unsigned short* __restrict__ Wpc,
                                                       const float* __restrict__ bpc,
                                                       const float* __restrict__ uf,
                                                       const unsigned short* __restrict__ Wrc,
                                                       const int* __restrict__ pair_idx,
                                                       float* __restrict__ part) {
    // overlay: [As 16KB | Bs 16KB]  with  [Ts 128x136 bf16 (34816B) | Ws 64x136 bf16 (17408B)]
    __shared__ __align__(16) char smem[52224];
    unsigned short* As = (unsigned short*)smem;
    unsigned short* Bs = (unsigned short*)(smem + 16384);
    unsigned short* Ts = (unsigned short*)smem;
    unsigned short* Ws = (unsigned short*)(smem + 34816);
    __shared__ int his[128], tis[128];

    const int eblk = blockIdx.x & 255;   // 256 edge-blocks of 128
    const int pblk = blockIdx.x >> 8;    // 4 P-quarters of 1024
    const int e0 = eblk * 128;
    const int c0 = pblk * (PDIM / PSPLIT);
    const int t = threadIdx.x;
    const int w = t >> 6, L = t & 63;
    const int quad = L >> 4, ln = L & 15;
    const int wr = (w >> 1) * 64, wc = (w & 1) * 64;
    const int srow = L >> 3, sc = L & 7;

    if (t < 128) {
        his[t] = pair_idx[2 * (e0 + t)];
        tis[t] = pair_idx[2 * (e0 + t) + 1];
    }
    __syncthreads();

    f32x4 rel[2][4] = {};  // rows w*32 + 16*i3 + (quad*4+r), cols 16*j3 + ln

    for (int pc = 0; pc < PDIM / PSPLIT; pc += 128) {
        const int p0 = c0 + pc;
        f32x4 acc[4][4] = {};
        for (int kt = 0; kt < 16; ++kt) {
            const int k0 = kt * 64;
#pragma unroll
            for (int s = 0; s < 4; ++s) {
                const int issue = w * 4 + s;
                const int row = issue * 8 + srow;
                const int ch = sc ^ (row & 7);
                const int ridx = (k0 < H) ? his[row] : tis[row];
                gload_lds16(Erep + (size_t)ridx * TWOH + k0 + ch * 8, &As[issue * 512]);
                gload_lds16(Wpc + (size_t)(p0 + row) * TWOH + k0 + ch * 8, &Bs[issue * 512]);
            }
            __syncthreads();
#pragma unroll
            for (int kk = 0; kk < 2; ++kk) {
                short8 a[4], b[4];
#pragma unroll
                for (int i = 0; i < 4; ++i) {
                    const int row = wr + 16 * i + ln;
                    const int ch = (kk * 4 + quad) ^ (row & 7);
                    a[i] = *(const short8*)&As[row * 64 + ch * 8];
                }
#pragma unroll
                for (int j = 0; j < 4; ++j) {
                    const int row = wc + 16 * j + ln;
                    const int ch = (kk * 4 + quad) ^ (row & 7);
                    b[j] = *(const short8*)&Bs[row * 64 + ch * 8];
                }
#pragma unroll
                for (int i = 0; i < 4; ++i)
#pragma unroll
                    for (int j = 0; j < 4; ++j)
                        acc[i][j] = __builtin_amdgcn_mfma_f32_16x16x32_bf16(a[i], b[j], acc[i][j], 0, 0, 0);
            }
            __syncthreads();
        }
        // ---- per-chunk epilogue: Ts = bf16((acc + b_pc) * uf); stage W_rc chunk ----
        float bv[4];
#pragma unroll
        for (int j = 0; j < 4; ++j) bv[j] = bpc[p0 + wc + 16 * j + ln];
#pragma unroll
        for (int i = 0; i < 4; ++i) {
#pragma unroll
            for (int r = 0; r < 4; ++r) {
                const int rowe = wr + 16 * i + quad * 4 + r;
                const float* ufrow = uf + (size_t)(e0 + rowe) * PDIM + p0 + wc + ln;
#pragma unroll
                for (int j = 0; j < 4; ++j) {
                    const float v = (acc[i][j][r] + bv[j]) * ufrow[16 * j];
                    Ts[rowe * 136 + wc + 16 * j + ln] = f2bf(v);
                }
            }
        }
#pragma unroll
        for (int s = 0; s < 4; ++s) {
            const int slot = t + s * 256;  // 0..1023: 64 rows x 16 col-groups
            const int row = slot >> 4;
            const int cg = slot & 15;
            const short8 v = *(const short8*)&Wrc[(size_t)row * PDIM + p0 + cg * 8];
            *(short8*)&Ws[row * 136 + cg * 8] = v;
        }
        __syncthreads();
        // ---- GEMM3 partial: rel += Ts(128x128) @ Ws(64x128)^T, wave w does rows w*32..+31 ----
#pragma unroll
        for (int kk = 0; kk < 4; ++kk) {
            short8 a3[2], b3[4];
#pragma unroll
            for (int i3 = 0; i3 < 2; ++i3) {
                const int rowe = w * 32 + i3 * 16 + ln;
                a3[i3] = *(const short8*)&Ts[rowe * 136 + kk * 32 + quad * 8];
            }
#pragma unroll
            for (int j3 = 0; j3 < 4; ++j3) {
                const int rown = j3 * 16 + ln;
                b3[j3] = *(const short8*)&Ws[rown * 136 + kk * 32 + quad * 8];
            }
#pragma unroll
            for (int i3 = 0; i3 < 2; ++i3)
#pragma unroll
                for (int j3 = 0; j3 < 4; ++j3)
                    rel[i3][j3] = __builtin_amdgcn_mfma_f32_16x16x32_bf16(a3[i3], b3[j3], rel[i3][j3], 0, 0, 0);
        }
        __syncthreads();  // protect Ts/Ws before next chunk's As/Bs staging overwrites
    }
    // ---- partial store: part[pblk][e0+rowe][col] = rel ----
    float* pout = part + ((size_t)pblk * EDIM + e0) * 64;
#pragma unroll
    for (int i3 = 0; i3 < 2; ++i3)
#pragma unroll
        for (int j3 = 0; j3 < 4; ++j3) {
            const int col = j3 * 16 + ln;
#pragma unroll
            for (int r = 0; r < 4; ++r) {
                const int rowe = w * 32 + i3 * 16 + quad * 4 + r;
                pout[(size_t)rowe * 64 + col] = rel[i3][j3][r];
            }
        }
}

// out[e][c] = sum_p part[p][e][c] + b_rc[c] + freq[bias_idx[e]*R + c]
__global__ __launch_bounds__(256) void reduce_kernel(const float* __restrict__ part,
                                                     const float* __restrict__ brc,
                                                     const float* __restrict__ freq,
                                                     const int* __restrict__ pair_idx,
                                                     const int* __restrict__ obj_preds,
                                                     float* __restrict__ out) {
    const int idx = blockIdx.x * 256 + threadIdx.x;  // over EDIM*64
    const int e = idx >> 6, c = idx & 63;
    if (c < RDIM) {
        float s = part[idx] + part[idx + EDIM * 64] + part[idx + 2 * EDIM * 64] +
                  part[idx + 3 * EDIM * 64];
        const int hi = pair_idx[2 * e];
        const int ti = pair_idx[2 * e + 1];
        s += brc[c] + freq[(obj_preds[hi] * CDIM + obj_preds[ti]) * RDIM + c];
        out[(size_t)e * RDIM + c] = s;
    }
}

extern "C" void kernel_launch(void* const* d_in, const int* in_sizes, int n_in,
                              void* d_out, int out_size, void* d_ws, size_t ws_size,
                              hipStream_t stream) {
    const float* edge_ctx = (const float*)d_in[0];
    const float* uf       = (const float*)d_in[1];
    const float* W_pe     = (const float*)d_in[2];
    const float* b_pe     = (const float*)d_in[3];
    const float* W_pc     = (const float*)d_in[4];
    const float* b_pc     = (const float*)d_in[5];
    const float* W_rc     = (const float*)d_in[6];
    const float* b_rc     = (const float*)d_in[7];
    const float* freq     = (const float*)d_in[8];
    const int* pair_idx   = (const int*)d_in[9];
    const int* obj_preds  = (const int*)d_in[10];
    float* out = (float*)d_out;

    unsigned short* ec_bf   = (unsigned short*)d_ws;          // 4096*512
    unsigned short* wpe_bf  = ec_bf + (size_t)NDIM * H;       // 1024*512
    unsigned short* erep_bf = wpe_bf + (size_t)TWOH * H;      // 4096*1024
    unsigned short* wpc_bf  = erep_bf + (size_t)NDIM * TWOH;  // 4096*1024
    unsigned short* wrc_bf  = wpc_bf + (size_t)PDIM * TWOH;   // 64*4096
    float* part = (float*)(wrc_bf + (size_t)64 * PDIM);       // PSPLIT*EDIM*64 f32

    cvt_bf16_kernel<<<(NDIM * H) / 1024, 256, 0, stream>>>(edge_ctx, ec_bf, NDIM * H);
    cvt_bf16_kernel<<<(TWOH * H) / 1024, 256, 0, stream>>>(W_pe, wpe_bf, TWOH * H);
    cvt_bf16_kernel<<<(PDIM * TWOH) / 1024, 256, 0, stream>>>(W_pc, wpc_bf, PDIM * TWOH);
    cvt_wrc_kernel<<<(64 * PDIM) / 1024, 256, 0, stream>>>(W_rc, wrc_bf);
    gemm1_kernel<<<256, 256, 0, stream>>>(ec_bf, wpe_bf, b_pe, erep_bf);
    fused_kernel<<<256 * PSPLIT, 256, 0, stream>>>(erep_bf, wpc_bf, b_pc, uf, wrc_bf,
                                                   pair_idx, part);
    reduce_kernel<<<(EDIM * 64) / 256, 256, 0, stream>>>(part, b_rc, freq, pair_idx,
                                                         obj_preds, out);
}

// Round 2
// 1071.752 us; speedup vs baseline: 1.8307x; 1.5416x over previous
//
#include <hip/hip_runtime.h>

#define H 512
#define TWOH 1024
#define PDIM 4096
#define CDIM 151
#define RDIM 51
#define NDIM 4096
#define EDIM 32768
#define PSPLIT 4

typedef __attribute__((ext_vector_type(8))) short short8;
typedef __attribute__((ext_vector_type(4))) float f32x4;

__device__ __forceinline__ unsigned short f2bf(float f) {
    union { float f; unsigned u; } x;
    x.f = f;
    unsigned r = x.u + 0x7fffu + ((x.u >> 16) & 1u);
    return (unsigned short)(r >> 16);
}

__device__ __forceinline__ void gload_lds16(const void* g, void* l) {
    __builtin_amdgcn_global_load_lds((const __attribute__((address_space(1))) void*)g,
                                     (__attribute__((address_space(3))) void*)l, 16, 0, 0);
}

// All 4 bf16 conversions in one launch.
// blocks: [0,2048) ec | [2048,2560) wpe | [2560,6656) wpc | [6656,6912) wrc(padded 64 rows)
__global__ __launch_bounds__(256) void cvt_all_kernel(const float* __restrict__ ec,
                                                      const float* __restrict__ wpe,
                                                      const float* __restrict__ wpc,
                                                      const float* __restrict__ wrc,
                                                      unsigned short* __restrict__ dec,
                                                      unsigned short* __restrict__ dwpe,
                                                      unsigned short* __restrict__ dwpc,
                                                      unsigned short* __restrict__ dwrc) {
    const int b = blockIdx.x;
    if (b < 2048) {
        const int i = (b * 256 + threadIdx.x) * 4;
        float4 v = *(const float4*)(ec + i);
        ushort4 o;
        o.x = f2bf(v.x); o.y = f2bf(v.y); o.z = f2bf(v.z); o.w = f2bf(v.w);
        *(ushort4*)(dec + i) = o;
    } else if (b < 2560) {
        const int i = ((b - 2048) * 256 + threadIdx.x) * 4;
        float4 v = *(const float4*)(wpe + i);
        ushort4 o;
        o.x = f2bf(v.x); o.y = f2bf(v.y); o.z = f2bf(v.z); o.w = f2bf(v.w);
        *(ushort4*)(dwpe + i) = o;
    } else if (b < 6656) {
        const int i = ((b - 2560) * 256 + threadIdx.x) * 4;
        float4 v = *(const float4*)(wpc + i);
        ushort4 o;
        o.x = f2bf(v.x); o.y = f2bf(v.y); o.z = f2bf(v.z); o.w = f2bf(v.w);
        *(ushort4*)(dwpc + i) = o;
    } else {
        const int i = ((b - 6656) * 256 + threadIdx.x) * 4;
        const int r = i >> 12;
        const int c = i & 4095;
        ushort4 o;
        if (r < RDIM) {
            float4 v = *(const float4*)(wrc + (size_t)r * PDIM + c);
            o.x = f2bf(v.x); o.y = f2bf(v.y); o.z = f2bf(v.z); o.w = f2bf(v.w);
        } else {
            o.x = 0; o.y = 0; o.z = 0; o.w = 0;
        }
        *(ushort4*)(dwrc + i) = o;
    }
}

// edge_rep = edge_ctx @ W_pe.T + b_pe (4096x1024) bf16 out. 2-phase pipelined.
__global__ __launch_bounds__(256, 2) void gemm1_kernel(const unsigned short* __restrict__ A,
                                                       const unsigned short* __restrict__ B,
                                                       const float* __restrict__ bias,
                                                       unsigned short* __restrict__ Crep) {
    __shared__ __align__(16) char smem[65536];  // dbuf: [As|Bs 32KB] x2
    const int bx = blockIdx.x & 7;
    const int by = blockIdx.x >> 3;
    const int t = threadIdx.x;
    const int w = t >> 6, L = t & 63;
    const int quad = L >> 4, ln = L & 15;
    const int wr = (w >> 1) * 64, wc = (w & 1) * 64;
    const int srow = L >> 3, sc = L & 7;

    f32x4 acc[4][4] = {};
    // prologue: stage kt=0 into buf0
    {
        unsigned short* As = (unsigned short*)smem;
        unsigned short* Bs = As + 8192;
#pragma unroll
        for (int s = 0; s < 4; ++s) {
            const int issue = w * 4 + s;
            const int row = issue * 8 + srow;
            const int ch = sc ^ (row & 7);
            gload_lds16(A + (size_t)(by * 128 + row) * H + ch * 8, &As[issue * 512]);
            gload_lds16(B + (size_t)(bx * 128 + row) * H + ch * 8, &Bs[issue * 512]);
        }
    }
    asm volatile("s_waitcnt vmcnt(0)" ::: "memory");
    __builtin_amdgcn_s_barrier();

#pragma unroll 2
    for (int kt = 0; kt < 8; ++kt) {
        const int cur = kt & 1;
        unsigned short* Asc = (unsigned short*)(smem + cur * 32768);
        unsigned short* Bsc = Asc + 8192;
        if (kt < 7) {
            const int k0 = (kt + 1) * 64;
            unsigned short* Asn = (unsigned short*)(smem + (cur ^ 1) * 32768);
            unsigned short* Bsn = Asn + 8192;
#pragma unroll
            for (int s = 0; s < 4; ++s) {
                const int issue = w * 4 + s;
                const int row = issue * 8 + srow;
                const int ch = sc ^ (row & 7);
                gload_lds16(A + (size_t)(by * 128 + row) * H + k0 + ch * 8, &Asn[issue * 512]);
                gload_lds16(B + (size_t)(bx * 128 + row) * H + k0 + ch * 8, &Bsn[issue * 512]);
            }
        }
#pragma unroll
        for (int kk = 0; kk < 2; ++kk) {
            short8 a[4], b[4];
#pragma unroll
            for (int i = 0; i < 4; ++i) {
                const int row = wr + 16 * i + ln;
                const int ch = (kk * 4 + quad) ^ (row & 7);
                a[i] = *(const short8*)&Asc[row * 64 + ch * 8];
            }
#pragma unroll
            for (int j = 0; j < 4; ++j) {
                const int row = wc + 16 * j + ln;
                const int ch = (kk * 4 + quad) ^ (row & 7);
                b[j] = *(const short8*)&Bsc[row * 64 + ch * 8];
            }
            __builtin_amdgcn_s_setprio(1);
#pragma unroll
            for (int i = 0; i < 4; ++i)
#pragma unroll
                for (int j = 0; j < 4; ++j)
                    acc[i][j] = __builtin_amdgcn_mfma_f32_16x16x32_bf16(a[i], b[j], acc[i][j], 0, 0, 0);
            __builtin_amdgcn_s_setprio(0);
        }
        asm volatile("s_waitcnt vmcnt(0)" ::: "memory");
        __builtin_amdgcn_s_barrier();
    }
#pragma unroll
    for (int i = 0; i < 4; ++i)
#pragma unroll
        for (int j = 0; j < 4; ++j) {
            const int col = bx * 128 + wc + 16 * j + ln;
            const float bv = bias[col];
#pragma unroll
            for (int r = 0; r < 4; ++r) {
                const int row = by * 128 + wr + 16 * i + quad * 4 + r;
                Crep[(size_t)row * TWOH + col] = f2bf(acc[i][j][r] + bv);
            }
        }
}

// Fused: GEMM2 (gathered edge_rep @ W_pc.T + b_pc) * uf -> LDS -> GEMM3 partial (@ W_rc.T)
// 2-phase pipelined k-loop; P reduction split across PSPLIT blocks.
__global__ __launch_bounds__(256, 2) void fused_kernel(const unsigned short* __restrict__ Erep,
                                                       const unsigned short* __restrict__ Wpc,
                                                       const float* __restrict__ bpc,
                                                       const float* __restrict__ uf,
                                                       const unsigned short* __restrict__ Wrc,
                                                       const int* __restrict__ pair_idx,
                                                       float* __restrict__ part) {
    // dbuf: [buf0 As|Bs 32KB][buf1 As|Bs 32KB]; epilogue overlay Ts 128x136, Ws 64x136
    __shared__ __align__(16) char smem[65536];
    unsigned short* Ts = (unsigned short*)smem;
    unsigned short* Ws = (unsigned short*)(smem + 34816);
    __shared__ int his[128], tis[128];

    const int eblk = blockIdx.x & 255;
    const int pblk = blockIdx.x >> 8;
    const int e0 = eblk * 128;
    const int c0 = pblk * (PDIM / PSPLIT);
    const int t = threadIdx.x;
    const int w = t >> 6, L = t & 63;
    const int quad = L >> 4, ln = L & 15;
    const int wr = (w >> 1) * 64, wc = (w & 1) * 64;
    const int srow = L >> 3, sc = L & 7;

    if (t < 128) {
        his[t] = pair_idx[2 * (e0 + t)];
        tis[t] = pair_idx[2 * (e0 + t) + 1];
    }
    __syncthreads();

    // per-thread staging row indices (constant over chunks/tiles)
    int hid[4], tid_[4];
#pragma unroll
    for (int s = 0; s < 4; ++s) {
        const int row = (w * 4 + s) * 8 + srow;
        hid[s] = his[row];
        tid_[s] = tis[row];
    }

    f32x4 rel[2][4] = {};  // rows w*32 + 16*i3 + (quad*4+r), cols 16*j3 + ln

    for (int pc = 0; pc < PDIM / PSPLIT; pc += 128) {
        const int p0 = c0 + pc;
        f32x4 acc[4][4] = {};

        // prologue: stage kt=0 into buf0 (after trailing barrier of prev chunk)
        {
            unsigned short* As = (unsigned short*)smem;
            unsigned short* Bs = As + 8192;
#pragma unroll
            for (int s = 0; s < 4; ++s) {
                const int issue = w * 4 + s;
                const int row = issue * 8 + srow;
                const int ch = sc ^ (row & 7);
                gload_lds16(Erep + (size_t)hid[s] * TWOH + ch * 8, &As[issue * 512]);
                gload_lds16(Wpc + (size_t)(p0 + row) * TWOH + ch * 8, &Bs[issue * 512]);
            }
        }
        asm volatile("s_waitcnt vmcnt(0)" ::: "memory");
        __builtin_amdgcn_s_barrier();

#pragma unroll 2
        for (int kt = 0; kt < 16; ++kt) {
            const int cur = kt & 1;
            unsigned short* Asc = (unsigned short*)(smem + cur * 32768);
            unsigned short* Bsc = Asc + 8192;
            if (kt < 15) {
                const int k0 = (kt + 1) * 64;
                unsigned short* Asn = (unsigned short*)(smem + (cur ^ 1) * 32768);
                unsigned short* Bsn = Asn + 8192;
#pragma unroll
                for (int s = 0; s < 4; ++s) {
                    const int issue = w * 4 + s;
                    const int row = issue * 8 + srow;
                    const int ch = sc ^ (row & 7);
                    const int ridx = (k0 < H) ? hid[s] : tid_[s];
                    gload_lds16(Erep + (size_t)ridx * TWOH + k0 + ch * 8, &Asn[issue * 512]);
                    gload_lds16(Wpc + (size_t)(p0 + row) * TWOH + k0 + ch * 8, &Bsn[issue * 512]);
                }
            }
#pragma unroll
            for (int kk = 0; kk < 2; ++kk) {
                short8 a[4], b[4];
#pragma unroll
                for (int i = 0; i < 4; ++i) {
                    const int row = wr + 16 * i + ln;
                    const int ch = (kk * 4 + quad) ^ (row & 7);
                    a[i] = *(const short8*)&Asc[row * 64 + ch * 8];
                }
#pragma unroll
                for (int j = 0; j < 4; ++j) {
                    const int row = wc + 16 * j + ln;
                    const int ch = (kk * 4 + quad) ^ (row & 7);
                    b[j] = *(const short8*)&Bsc[row * 64 + ch * 8];
                }
                __builtin_amdgcn_s_setprio(1);
#pragma unroll
                for (int i = 0; i < 4; ++i)
#pragma unroll
                    for (int j = 0; j < 4; ++j)
                        acc[i][j] = __builtin_amdgcn_mfma_f32_16x16x32_bf16(a[i], b[j], acc[i][j], 0, 0, 0);
                __builtin_amdgcn_s_setprio(0);
            }
            asm volatile("s_waitcnt vmcnt(0)" ::: "memory");
            __builtin_amdgcn_s_barrier();
        }

        // ---- per-chunk epilogue: Ts = bf16((acc + b_pc) * uf); stage W_rc chunk ----
        float bv[4];
#pragma unroll
        for (int j = 0; j < 4; ++j) bv[j] = bpc[p0 + wc + 16 * j + ln];
#pragma unroll
        for (int i = 0; i < 4; ++i) {
#pragma unroll
            for (int r = 0; r < 4; ++r) {
                const int rowe = wr + 16 * i + quad * 4 + r;
                const float* ufrow = uf + (size_t)(e0 + rowe) * PDIM + p0 + wc + ln;
#pragma unroll
                for (int j = 0; j < 4; ++j) {
                    const float v = (acc[i][j][r] + bv[j]) * ufrow[16 * j];
                    Ts[rowe * 136 + wc + 16 * j + ln] = f2bf(v);
                }
            }
        }
#pragma unroll
        for (int s = 0; s < 4; ++s) {
            const int slot = t + s * 256;  // 64 rows x 16 col-groups
            const int row = slot >> 4;
            const int cg = slot & 15;
            const short8 v = *(const short8*)&Wrc[(size_t)row * PDIM + p0 + cg * 8];
            *(short8*)&Ws[row * 136 + cg * 8] = v;
        }
        __syncthreads();
        // ---- GEMM3 partial: rel += Ts(128x128) @ Ws(64x128)^T ----
#pragma unroll
        for (int kk = 0; kk < 4; ++kk) {
            short8 a3[2], b3[4];
#pragma unroll
            for (int i3 = 0; i3 < 2; ++i3) {
                const int rowe = w * 32 + i3 * 16 + ln;
                a3[i3] = *(const short8*)&Ts[rowe * 136 + kk * 32 + quad * 8];
            }
#pragma unroll
            for (int j3 = 0; j3 < 4; ++j3) {
                const int rown = j3 * 16 + ln;
                b3[j3] = *(const short8*)&Ws[rown * 136 + kk * 32 + quad * 8];
            }
#pragma unroll
            for (int i3 = 0; i3 < 2; ++i3)
#pragma unroll
                for (int j3 = 0; j3 < 4; ++j3)
                    rel[i3][j3] = __builtin_amdgcn_mfma_f32_16x16x32_bf16(a3[i3], b3[j3], rel[i3][j3], 0, 0, 0);
        }
        __syncthreads();  // protect Ts/Ws before next chunk's staging overwrites
    }
    // ---- partial store ----
    float* pout = part + ((size_t)pblk * EDIM + e0) * 64;
#pragma unroll
    for (int i3 = 0; i3 < 2; ++i3)
#pragma unroll
        for (int j3 = 0; j3 < 4; ++j3) {
            const int col = j3 * 16 + ln;
#pragma unroll
            for (int r = 0; r < 4; ++r) {
                const int rowe = w * 32 + i3 * 16 + quad * 4 + r;
                pout[(size_t)rowe * 64 + col] = rel[i3][j3][r];
            }
        }
}

// out[e][c] = sum_p part[p][e][c] + b_rc[c] + freq[bias_idx[e]*R + c]
__global__ __launch_bounds__(256) void reduce_kernel(const float* __restrict__ part,
                                                     const float* __restrict__ brc,
                                                     const float* __restrict__ freq,
                                                     const int* __restrict__ pair_idx,
                                                     const int* __restrict__ obj_preds,
                                                     float* __restrict__ out) {
    const int idx = blockIdx.x * 256 + threadIdx.x;
    const int e = idx >> 6, c = idx & 63;
    if (c < RDIM) {
        float s = part[idx] + part[idx + EDIM * 64] + part[idx + 2 * EDIM * 64] +
                  part[idx + 3 * EDIM * 64];
        const int hi = pair_idx[2 * e];
        const int ti = pair_idx[2 * e + 1];
        s += brc[c] + freq[(obj_preds[hi] * CDIM + obj_preds[ti]) * RDIM + c];
        out[(size_t)e * RDIM + c] = s;
    }
}

extern "C" void kernel_launch(void* const* d_in, const int* in_sizes, int n_in,
                              void* d_out, int out_size, void* d_ws, size_t ws_size,
                              hipStream_t stream) {
    const float* edge_ctx = (const float*)d_in[0];
    const float* uf       = (const float*)d_in[1];
    const float* W_pe     = (const float*)d_in[2];
    const float* b_pe     = (const float*)d_in[3];
    const float* W_pc     = (const float*)d_in[4];
    const float* b_pc     = (const float*)d_in[5];
    const float* W_rc     = (const float*)d_in[6];
    const float* b_rc     = (const float*)d_in[7];
    const float* freq     = (const float*)d_in[8];
    const int* pair_idx   = (const int*)d_in[9];
    const int* obj_preds  = (const int*)d_in[10];
    float* out = (float*)d_out;

    unsigned short* ec_bf   = (unsigned short*)d_ws;          // 4096*512
    unsigned short* wpe_bf  = ec_bf + (size_t)NDIM * H;       // 1024*512
    unsigned short* erep_bf = wpe_bf + (size_t)TWOH * H;      // 4096*1024
    unsigned short* wpc_bf  = erep_bf + (size_t)NDIM * TWOH;  // 4096*1024
    unsigned short* wrc_bf  = wpc_bf + (size_t)PDIM * TWOH;   // 64*4096
    float* part = (float*)(wrc_bf + (size_t)64 * PDIM);       // PSPLIT*EDIM*64 f32

    cvt_all_kernel<<<6912, 256, 0, stream>>>(edge_ctx, W_pe, W_pc, W_rc,
                                             ec_bf, wpe_bf, wpc_bf, wrc_bf);
    gemm1_kernel<<<256, 256, 0, stream>>>(ec_bf, wpe_bf, b_pe, erep_bf);
    fused_kernel<<<256 * PSPLIT, 256, 0, stream>>>(erep_bf, wpc_bf, b_pc, uf, wrc_bf,
                                                   pair_idx, part);
    reduce_kernel<<<(EDIM * 64) / 256, 256, 0, stream>>>(part, b_rc, freq, pair_idx,
                                                         obj_preds, out);
}